// Round 12
// baseline (424.904 us; speedup 1.0000x reference)
//
#include <hip/hip_runtime.h>

#define EPS_F 1e-5f
#define SCALE_F 0.02f

using short8  = __attribute__((ext_vector_type(8))) short;
using floatx4 = __attribute__((ext_vector_type(4))) float;

__device__ __forceinline__ unsigned short f2bf(float f) {
  unsigned u = __float_as_uint(f);
  return (unsigned short)((u + 0x7fffu + ((u >> 16) & 1u)) >> 16);
}

// ---------------- merged prep: weights+BN (blocks 0..127), x->NHWC (128..1919)
__global__ void prep_all(const float* __restrict__ w1, const float* __restrict__ w2,
                         unsigned short* __restrict__ ap1, unsigned short* __restrict__ ap2,
                         const float* g1, const float* b1, const float* m1, const float* v1,
                         const float* g2, const float* b2, const float* m2, const float* v2,
                         float* bnp,
                         const float* __restrict__ x, unsigned short* __restrict__ xb,
                         unsigned short* __restrict__ abuf) {
  __shared__ __align__(16) unsigned short sh[9248];   // max(32*289, 28*264)
  const int bx  = blockIdx.x;
  const int tid = threadIdx.x;

  if (bx < 128) {
    unsigned short (*sgn)[289] = (unsigned short (*)[289])sh;
    const int sel = bx >> 6;
    const int tile = bx & 63;
    const int co0 = (tile >> 3) * 32;
    const int ci0 = (tile & 7) * 32;
    const float* __restrict__ w = sel ? w2 : w1;
    unsigned short* __restrict__ ap = sel ? ap2 : ap1;

#pragma unroll
    for (int k = 0; k < 9; ++k) {
      int u = tid + k * 256;          // 0..2303 float4 units
      int co_i = u / 72;              // 72 float4 per co row
      int rem  = u - co_i * 72;
      const float* src = w + ((size_t)(co0 + co_i) * 256 + ci0) * 9 + rem * 4;
      floatx4 f = *(const floatx4*)src;
#pragma unroll
      for (int q = 0; q < 4; ++q) {
        float v = f[q];
        sgn[co_i][rem * 4 + q] =
            (v > 0.f) ? (unsigned short)0x3F80 : ((v < 0.f) ? (unsigned short)0xBF80 : (unsigned short)0);
      }
    }
    __syncthreads();

    for (int u = tid; u < 1152; u += 256) {
      int co_i = u & 31;
      int c8l  = (u >> 5) & 3;
      int t    = u >> 7;              // 0..8
      short8 o;
#pragma unroll
      for (int j = 0; j < 8; ++j)
        o[j] = (short)sgn[co_i][(c8l * 8 + j) * 9 + t];
      size_t dst = (size_t)(t * 32 + (ci0 >> 3) + c8l) * 2048 + (size_t)(co0 + co_i) * 8;
      *(short8*)(ap + dst) = o;
    }

    if (bx == 0) {
      int c = tid;
      float i1 = g1[c] * rsqrtf(v1[c] + EPS_F);
      bnp[c]       = SCALE_F * i1;
      bnp[256 + c] = b1[c] - m1[c] * i1;
      float i2 = g2[c] * rsqrtf(v2[c] + EPS_F);
      bnp[512 + c] = SCALE_F * i2;
      bnp[768 + c] = b2[c] - m2[c] * i2;
    }
  } else {
    unsigned short* xt = sh;          // [28][264]
    int p = bx - 128;
    int h = p % 28;                   // 0..27
    int n = p / 28;                   // 0..63

#pragma unroll
    for (int k = 0; k < 7; ++k) {
      int u = tid + k * 256;          // 0..1791
      int ci = u / 7;
      int f4 = u - ci * 7;
      const float* src = x + ((size_t)n * 256 + ci) * 784 + h * 28 + f4 * 4;
      floatx4 f = *(const floatx4*)src;
#pragma unroll
      for (int q = 0; q < 4; ++q)
        xt[(f4 * 4 + q) * 264 + ci] = f2bf(f[q]);
    }
    __syncthreads();

    unsigned short* xd = xb + ((size_t)n * 900 + (h + 1) * 30 + 1) * 256;
    for (int u = tid; u < 896; u += 256) {
      int px = u >> 5;
      int c8 = (u & 31) * 8;
      *(short8*)(xd + (size_t)px * 256 + c8) = *(const short8*)&xt[px * 264 + c8];
    }

    {
      int bufi = tid >> 7, side = (tid >> 6) & 1, c4 = tid & 63;
      unsigned short* bb = (bufi ? abuf : xb) + ((size_t)n * 900 + (h + 1) * 30 + side * 29) * 256;
      ushort4 z = {0, 0, 0, 0};
      *(ushort4*)(bb + c4 * 4) = z;
    }
    if (h == 0 || h == 27) {
      int row = (h == 0) ? 0 : 29;
      for (int u = tid; u < 3840; u += 256) {
        int bufi = u / 1920;
        int r    = u - bufi * 1920;
        int px   = r >> 6, c4 = r & 63;
        unsigned short* bb = (bufi ? abuf : xb) + ((size_t)n * 900 + row * 30 + px) * 256;
        ushort4 z = {0, 0, 0, 0};
        *(ushort4*)(bb + c4 * 4) = z;
      }
    }
  }
}

// ---------------- conv (implicit GEMM, halo-tiled) — 4-wave, t fully unrolled
// Block: 256 thr = 4 waves. Macro-tile: 256 co x 112 sp (4 rows) of one image.
// ci-block 64: LDS halo 6 rows x 30 px, XOR-swizzled pitch-64, double-buffered.
// Staging via global_load_lds (linear LDS dest, inverse-swizzled global src).
// Rotating 7x short8 B buffer refilled inside the MFMA burst (4:1 interleave).
// NEW vs round 10: the 9-tap t-loop is FULLY UNROLLED -> D walk and A-chunk
// indices are compile-time; per-read address VALU shrinks, loop control gone.
template<int STAGE>
__global__ __launch_bounds__(256, 2) void bconv(
    const unsigned short* __restrict__ Bin,
    const unsigned short* __restrict__ Apack,
    const float* __restrict__ bnp,
    unsigned short* __restrict__ aout,
    const float* __restrict__ xres,
    float* __restrict__ out)
{
  __shared__ __align__(16) unsigned short smem[STAGE == 1 ? 29568 : 24576];

  const int tid  = threadIdx.x;
  const int lane = tid & 63;
  const int wv   = tid >> 6;
  const int quad = lane >> 4;
  const int l16  = lane & 15;

  // XCD-aware swizzle: 448 blocks = 8 XCDs x 56.
  int flat = blockIdx.y * 7 + blockIdx.x;
  int idx  = (flat & 7) * 56 + (flat >> 3);
  const int n     = idx / 7;
  const int spBlk = idx - n * 7;

  const int prow0 = 4 * spBlk;
  const unsigned short* bsrc = Bin + ((size_t)n * 900 + prow0 * 30) * 256;
  const int coW = wv * 64;

  int pxS[7];
#pragma unroll
  for (int s = 0; s < 7; ++s) {
    int lm = s * 16 + l16;
    int hl = lm / 28;
    int w  = lm - hl * 28;
    pxS[s] = hl * 30 + w;
  }

  int goff0, goff1, goff2, goff3, goff4, goff5;
  {
#define MKGOFF(dst, r) { int v = (r) * 256 + tid; int px = v >> 3; \
    if (px > 179) px = 179; int c = (v & 7) ^ (px & 7); dst = px * 256 + c * 8; }
    MKGOFF(goff0, 0) MKGOFF(goff1, 1) MKGOFF(goff2, 2)
    MKGOFF(goff3, 3) MKGOFF(goff4, 4) MKGOFF(goff5, 5)
#undef MKGOFF
  }

#define STAGE_CB(cbi, bufsel) { \
  unsigned short* lb = smem + (bufsel) * 12288 + wv * 512; \
  const unsigned short* gb = bsrc + (cbi) * 64; \
  __builtin_amdgcn_global_load_lds((const __attribute__((address_space(1))) void*)(gb + goff0), \
      (__attribute__((address_space(3))) void*)(lb + 0 * 2048), 16, 0, 0); \
  __builtin_amdgcn_global_load_lds((const __attribute__((address_space(1))) void*)(gb + goff1), \
      (__attribute__((address_space(3))) void*)(lb + 1 * 2048), 16, 0, 0); \
  __builtin_amdgcn_global_load_lds((const __attribute__((address_space(1))) void*)(gb + goff2), \
      (__attribute__((address_space(3))) void*)(lb + 2 * 2048), 16, 0, 0); \
  __builtin_amdgcn_global_load_lds((const __attribute__((address_space(1))) void*)(gb + goff3), \
      (__attribute__((address_space(3))) void*)(lb + 3 * 2048), 16, 0, 0); \
  __builtin_amdgcn_global_load_lds((const __attribute__((address_space(1))) void*)(gb + goff4), \
      (__attribute__((address_space(3))) void*)(lb + 4 * 2048), 16, 0, 0); \
  __builtin_amdgcn_global_load_lds((const __attribute__((address_space(1))) void*)(gb + goff5), \
      (__attribute__((address_space(3))) void*)(lb + 5 * 2048), 16, 0, 0); }

#define LOADA(d0, d1, d2, d3, t, half, CQ8) { \
  const unsigned short* p = Apack + ((size_t)(((t) * 32 + (CQ8) + (half) * 4) * 256 + coW + l16)) * 8; \
  d0 = *(const short8*)p; \
  d1 = *(const short8*)(p + 16 * 8); \
  d2 = *(const short8*)(p + 32 * 8); \
  d3 = *(const short8*)(p + 48 * 8); }

// fill the rotating B buffer for a burst (7 ds_read_b128)
#define BFILL(fC, fD) { \
  _Pragma("unroll") \
  for (int s = 0; s < 7; ++s) { \
    int pe = pxS[s] + (fD); \
    bfr[s] = *(const short8*)&Blds[(pe << 6) + (((fC) ^ (pe & 7)) << 3)]; \
  } }

// MFMA burst consuming bfr, refilling bfr[s] for the NEXT burst per s-step
#define BREF(a0, a1, a2, a3, rC, rD) { \
  __builtin_amdgcn_s_setprio(1); \
  _Pragma("unroll") \
  for (int s = 0; s < 7; ++s) { \
    acc[0][s] = __builtin_amdgcn_mfma_f32_16x16x32_bf16(a0, bfr[s], acc[0][s], 0, 0, 0); \
    acc[1][s] = __builtin_amdgcn_mfma_f32_16x16x32_bf16(a1, bfr[s], acc[1][s], 0, 0, 0); \
    acc[2][s] = __builtin_amdgcn_mfma_f32_16x16x32_bf16(a2, bfr[s], acc[2][s], 0, 0, 0); \
    acc[3][s] = __builtin_amdgcn_mfma_f32_16x16x32_bf16(a3, bfr[s], acc[3][s], 0, 0, 0); \
    int pe2 = pxS[s] + (rD); \
    bfr[s] = *(const short8*)&Blds[(pe2 << 6) + (((rC) ^ (pe2 & 7)) << 3)]; \
  } \
  __builtin_amdgcn_s_setprio(0); }

// MFMA burst, consume only (last burst of a ci-block)
#define BONLY(a0, a1, a2, a3) { \
  __builtin_amdgcn_s_setprio(1); \
  _Pragma("unroll") \
  for (int s = 0; s < 7; ++s) { \
    acc[0][s] = __builtin_amdgcn_mfma_f32_16x16x32_bf16(a0, bfr[s], acc[0][s], 0, 0, 0); \
    acc[1][s] = __builtin_amdgcn_mfma_f32_16x16x32_bf16(a1, bfr[s], acc[1][s], 0, 0, 0); \
    acc[2][s] = __builtin_amdgcn_mfma_f32_16x16x32_bf16(a2, bfr[s], acc[2][s], 0, 0, 0); \
    acc[3][s] = __builtin_amdgcn_mfma_f32_16x16x32_bf16(a3, bfr[s], acc[3][s], 0, 0, 0); \
  } \
  __builtin_amdgcn_s_setprio(0); }

  floatx4 acc[4][7];
#pragma unroll
  for (int c = 0; c < 4; ++c)
#pragma unroll
    for (int s = 0; s < 7; ++s)
      acc[c][s] = (floatx4){0.f, 0.f, 0.f, 0.f};

  short8 A0, A1, A2, A3, N0, N1, N2, N3;
  short8 bfr[7];

  // prologue: async-stage ci-block 0 into buffer 0; preload tap0 A-pair.
  STAGE_CB(0, 0);
  LOADA(A0, A1, A2, A3, 0, 0, quad);
  LOADA(N0, N1, N2, N3, 0, 1, quad);
  __syncthreads();

#pragma unroll 1
  for (int cb = 0; cb < 4; ++cb) {
    unsigned short* Blds = smem + (cb & 1) * 12288;
    BFILL(quad, 0);                               // burst (t=0, half0)
    if (cb < 3) { STAGE_CB(cb + 1, (cb + 1) & 1); }   // fire-and-forget
    const int cq8 = cb * 8 + quad;
    // FULL UNROLL of the 9 taps: D and t compile-time constants.
#pragma unroll
    for (int t = 0; t < 8; ++t) {
      const int D  = (t < 3) ? t : ((t < 6) ? (t + 27) : (t + 54));   // kh*30+kw
      const int Dn = (t < 2) ? (t + 1) : ((t < 5) ? (t + 28) : (t + 55));
      BREF(A0, A1, A2, A3, 4 + quad, D);          // even burst (t,h0), refill (t,h1)
      LOADA(A0, A1, A2, A3, t + 1, 0, cq8);
      BREF(N0, N1, N2, N3, quad, Dn);             // odd burst (t,h1), refill (t+1,h0)
      LOADA(N0, N1, N2, N3, t + 1, 1, cq8);
    }
    // t = 8 (D == 62)
    BREF(A0, A1, A2, A3, 4 + quad, 62);           // refill (8,h1)
    BONLY(N0, N1, N2, N3);
    if (cb < 3) {
      LOADA(A0, A1, A2, A3, 0, 0, cq8 + 8);       // next cb tap0, pre-barrier
      LOADA(N0, N1, N2, N3, 0, 1, cq8 + 8);
      __syncthreads();
    }
  }

  // Epilogue. C/D layout: col(sp)=l16, row(co within 16-tile)=quad*4+reg.
  if (STAGE == 1) {
    __syncthreads();   // last cb's Blds reads done before overwrite
#pragma unroll
    for (int c = 0; c < 4; ++c) {
      int co = coW + c * 16 + quad * 4;
      floatx4 As = *(const floatx4*)(bnp + co);
      floatx4 Bs = *(const floatx4*)(bnp + 256 + co);
#pragma unroll
      for (int s = 0; s < 7; ++s) {
        int px = s * 16 + l16;
        ushort4 o;
        o.x = f2bf(fmaxf(acc[c][s][0] * As[0] + Bs[0], 0.f));
        o.y = f2bf(fmaxf(acc[c][s][1] * As[1] + Bs[1], 0.f));
        o.z = f2bf(fmaxf(acc[c][s][2] * As[2] + Bs[2], 0.f));
        o.w = f2bf(fmaxf(acc[c][s][3] * As[3] + Bs[3], 0.f));
        *(ushort4*)&smem[px * 264 + co] = o;
      }
    }
    __syncthreads();
    unsigned short* dst0 = aout + ((size_t)n * 900 + (prow0 + 1) * 30 + 1) * 256;
    for (int u = tid; u < 3584; u += 256) {   // 112 px * 32 groups of 8 co
      int px = u >> 5;
      int c8 = (u & 31) * 8;
      int r  = px / 28;
      int w  = px - r * 28;
      *(short8*)(dst0 + (size_t)(r * 30 + w) * 256 + c8) = *(const short8*)&smem[px * 264 + c8];
    }
  } else {
#pragma unroll
    for (int c = 0; c < 4; ++c) {
      int co = coW + c * 16 + quad * 4;
      floatx4 As = *(const floatx4*)(bnp + 512 + co);
      floatx4 Bs = *(const floatx4*)(bnp + 768 + co);
#pragma unroll
      for (int s = 0; s < 7; ++s) {
        int m = spBlk * 112 + s * 16 + l16;
#pragma unroll
        for (int r = 0; r < 4; ++r) {
          size_t oidx = ((size_t)n * 256 + co + r) * 784 + m;
          float v = acc[c][s][r] * As[r] + Bs[r] + xres[oidx];
          out[oidx] = fmaxf(v, 0.f);
        }
      }
    }
  }
#undef STAGE_CB
#undef LOADA
#undef BFILL
#undef BREF
#undef BONLY
}

// ---------------- launch ----------------

extern "C" void kernel_launch(void* const* d_in, const int* in_sizes, int n_in,
                              void* d_out, int out_size, void* d_ws, size_t ws_size,
                              hipStream_t stream) {
  const float* x  = (const float*)d_in[0];
  const float* w1 = (const float*)d_in[1];
  const float* g1 = (const float*)d_in[2];
  const float* b1 = (const float*)d_in[3];
  const float* m1 = (const float*)d_in[4];
  const float* v1 = (const float*)d_in[5];
  const float* w2 = (const float*)d_in[6];
  const float* g2 = (const float*)d_in[7];
  const float* b2 = (const float*)d_in[8];
  const float* m2 = (const float*)d_in[9];
  const float* v2 = (const float*)d_in[10];
  float* out = (float*)d_out;

  char* ws = (char*)d_ws;
  const size_t PADBUF = (size_t)64 * 900 * 256 * 2;   // 29,491,200 B
  const size_t WPACK  = 589824ull * 2;                 // 1,179,648 B
  unsigned short* xb   = (unsigned short*)ws;
  unsigned short* abuf = (unsigned short*)(ws + PADBUF);
  unsigned short* ap1  = (unsigned short*)(ws + 2 * PADBUF);
  unsigned short* ap2  = (unsigned short*)(ws + 2 * PADBUF + WPACK);
  float* bnp           = (float*)(ws + 2 * PADBUF + 2 * WPACK);

  prep_all<<<dim3(1920), 256, 0, stream>>>(w1, w2, ap1, ap2,
                                           g1, b1, m1, v1, g2, b2, m2, v2, bnp,
                                           x, xb, abuf);

  dim3 grid(7, 64);   // sp-tile, image
  bconv<1><<<grid, 256, 0, stream>>>(xb,   ap1, bnp, abuf, nullptr, nullptr);
  bconv<2><<<grid, 256, 0, stream>>>(abuf, ap2, bnp, nullptr, x, out);
}

// Round 13
// 219.791 us; speedup vs baseline: 1.9332x; 1.9332x over previous
//
#include <hip/hip_runtime.h>

#define EPS_F 1e-5f
#define SCALE_F 0.02f

using short8  = __attribute__((ext_vector_type(8))) short;
using floatx4 = __attribute__((ext_vector_type(4))) float;

__device__ __forceinline__ unsigned short f2bf(float f) {
  unsigned u = __float_as_uint(f);
  return (unsigned short)((u + 0x7fffu + ((u >> 16) & 1u)) >> 16);
}

// ---------------- merged prep: weights+BN (blocks 0..127), x->NHWC (128..1919)
__global__ void prep_all(const float* __restrict__ w1, const float* __restrict__ w2,
                         unsigned short* __restrict__ ap1, unsigned short* __restrict__ ap2,
                         const float* g1, const float* b1, const float* m1, const float* v1,
                         const float* g2, const float* b2, const float* m2, const float* v2,
                         float* bnp,
                         const float* __restrict__ x, unsigned short* __restrict__ xb,
                         unsigned short* __restrict__ abuf) {
  __shared__ __align__(16) unsigned short sh[9248];   // max(32*289, 28*264)
  const int bx  = blockIdx.x;
  const int tid = threadIdx.x;

  if (bx < 128) {
    unsigned short (*sgn)[289] = (unsigned short (*)[289])sh;
    const int sel = bx >> 6;
    const int tile = bx & 63;
    const int co0 = (tile >> 3) * 32;
    const int ci0 = (tile & 7) * 32;
    const float* __restrict__ w = sel ? w2 : w1;
    unsigned short* __restrict__ ap = sel ? ap2 : ap1;

#pragma unroll
    for (int k = 0; k < 9; ++k) {
      int u = tid + k * 256;          // 0..2303 float4 units
      int co_i = u / 72;              // 72 float4 per co row
      int rem  = u - co_i * 72;
      const float* src = w + ((size_t)(co0 + co_i) * 256 + ci0) * 9 + rem * 4;
      floatx4 f = *(const floatx4*)src;
#pragma unroll
      for (int q = 0; q < 4; ++q) {
        float v = f[q];
        sgn[co_i][rem * 4 + q] =
            (v > 0.f) ? (unsigned short)0x3F80 : ((v < 0.f) ? (unsigned short)0xBF80 : (unsigned short)0);
      }
    }
    __syncthreads();

    for (int u = tid; u < 1152; u += 256) {
      int co_i = u & 31;
      int c8l  = (u >> 5) & 3;
      int t    = u >> 7;              // 0..8
      short8 o;
#pragma unroll
      for (int j = 0; j < 8; ++j)
        o[j] = (short)sgn[co_i][(c8l * 8 + j) * 9 + t];
      size_t dst = (size_t)(t * 32 + (ci0 >> 3) + c8l) * 2048 + (size_t)(co0 + co_i) * 8;
      *(short8*)(ap + dst) = o;
    }

    if (bx == 0) {
      int c = tid;
      float i1 = g1[c] * rsqrtf(v1[c] + EPS_F);
      bnp[c]       = SCALE_F * i1;
      bnp[256 + c] = b1[c] - m1[c] * i1;
      float i2 = g2[c] * rsqrtf(v2[c] + EPS_F);
      bnp[512 + c] = SCALE_F * i2;
      bnp[768 + c] = b2[c] - m2[c] * i2;
    }
  } else {
    unsigned short* xt = sh;          // [28][264]
    int p = bx - 128;
    int h = p % 28;                   // 0..27
    int n = p / 28;                   // 0..63

#pragma unroll
    for (int k = 0; k < 7; ++k) {
      int u = tid + k * 256;          // 0..1791
      int ci = u / 7;
      int f4 = u - ci * 7;
      const float* src = x + ((size_t)n * 256 + ci) * 784 + h * 28 + f4 * 4;
      floatx4 f = *(const floatx4*)src;
#pragma unroll
      for (int q = 0; q < 4; ++q)
        xt[(f4 * 4 + q) * 264 + ci] = f2bf(f[q]);
    }
    __syncthreads();

    unsigned short* xd = xb + ((size_t)n * 900 + (h + 1) * 30 + 1) * 256;
    for (int u = tid; u < 896; u += 256) {
      int px = u >> 5;
      int c8 = (u & 31) * 8;
      *(short8*)(xd + (size_t)px * 256 + c8) = *(const short8*)&xt[px * 264 + c8];
    }

    {
      int bufi = tid >> 7, side = (tid >> 6) & 1, c4 = tid & 63;
      unsigned short* bb = (bufi ? abuf : xb) + ((size_t)n * 900 + (h + 1) * 30 + side * 29) * 256;
      ushort4 z = {0, 0, 0, 0};
      *(ushort4*)(bb + c4 * 4) = z;
    }
    if (h == 0 || h == 27) {
      int row = (h == 0) ? 0 : 29;
      for (int u = tid; u < 3840; u += 256) {
        int bufi = u / 1920;
        int r    = u - bufi * 1920;
        int px   = r >> 6, c4 = r & 63;
        unsigned short* bb = (bufi ? abuf : xb) + ((size_t)n * 900 + row * 30 + px) * 256;
        ushort4 z = {0, 0, 0, 0};
        *(ushort4*)(bb + c4 * 4) = z;
      }
    }
  }
}

// ---------------- conv (implicit GEMM, halo-tiled, 8-WAVE) ----------------
// Block: 512 thr = 8 waves. Macro-tile: 256 co x 112 sp (4 rows) of one image.
// Wave: 32 co x 112 sp -> acc[2][7] (56 AGPR); 120 regs total -> 4 waves/SIMD.
// ci-block 64: LDS halo 6 rows x 30 px, XOR-swizzled pitch-64, double-buffered;
// staged via global_load_lds (linear LDS dest, inverse-swizzled global src).
// vs round 11: s_setprio REMOVED (T5 is null/negative on lockstep barrier-
// synced structures, m190); otherwise identical to the measured best (223.2us).
template<int STAGE>
__global__ __launch_bounds__(512, 4) void bconv(
    const unsigned short* __restrict__ Bin,
    const unsigned short* __restrict__ Apack,
    const float* __restrict__ bnp,
    unsigned short* __restrict__ aout,
    const float* __restrict__ xres,
    float* __restrict__ out)
{
  __shared__ __align__(16) unsigned short smem[STAGE == 1 ? 29568 : 24576];

  const int tid  = threadIdx.x;
  const int lane = tid & 63;
  const int wv   = tid >> 6;        // 0..7
  const int quad = lane >> 4;
  const int l16  = lane & 15;

  // XCD-aware swizzle: 448 blocks = 8 XCDs x 56.
  int flat = blockIdx.y * 7 + blockIdx.x;
  int idx  = (flat & 7) * 56 + (flat >> 3);
  const int n     = idx / 7;
  const int spBlk = idx - n * 7;

  const int prow0 = 4 * spBlk;
  const unsigned short* bsrc = Bin + ((size_t)n * 900 + prow0 * 30) * 256;
  const int coW = wv * 32;          // 32 co per wave

  int pxS[7];
#pragma unroll
  for (int s = 0; s < 7; ++s) {
    int lm = s * 16 + l16;
    int hl = lm / 28;
    int w  = lm - hl * 28;
    pxS[s] = hl * 30 + w;
  }

  // staging source offsets: unit v = r*512 + tid (r=0..2, 1536 units incl. pad)
  int goff0, goff1, goff2;
  {
#define MKGOFF(dst, r) { int v = (r) * 512 + tid; int px = v >> 3; \
    if (px > 179) px = 179; int c = (v & 7) ^ (px & 7); dst = px * 256 + c * 8; }
    MKGOFF(goff0, 0) MKGOFF(goff1, 1) MKGOFF(goff2, 2)
#undef MKGOFF
  }

#define STAGE_CB(cbi, bufsel) { \
  unsigned short* lb = smem + (bufsel) * 12288 + wv * 512; \
  const unsigned short* gb = bsrc + (cbi) * 64; \
  __builtin_amdgcn_global_load_lds((const __attribute__((address_space(1))) void*)(gb + goff0), \
      (__attribute__((address_space(3))) void*)(lb + 0 * 4096), 16, 0, 0); \
  __builtin_amdgcn_global_load_lds((const __attribute__((address_space(1))) void*)(gb + goff1), \
      (__attribute__((address_space(3))) void*)(lb + 1 * 4096), 16, 0, 0); \
  __builtin_amdgcn_global_load_lds((const __attribute__((address_space(1))) void*)(gb + goff2), \
      (__attribute__((address_space(3))) void*)(lb + 2 * 4096), 16, 0, 0); }

#define LOADA2(d0, d1, t, half, CQ8) { \
  const unsigned short* p = Apack + ((size_t)(((t) * 32 + (CQ8) + (half) * 4) * 256 + coW + l16)) * 8; \
  d0 = *(const short8*)p; \
  d1 = *(const short8*)(p + 16 * 8); }

#define HALFMMA2(a0, a1, Cx, Dv) { \
  _Pragma("unroll") \
  for (int s = 0; s < 7; ++s) { \
    int pe = pxS[s] + (Dv); \
    short8 b = *(const short8*)&Blds[(pe << 6) + (((Cx) ^ (pe & 7)) << 3)]; \
    acc[0][s] = __builtin_amdgcn_mfma_f32_16x16x32_bf16(a0, b, acc[0][s], 0, 0, 0); \
    acc[1][s] = __builtin_amdgcn_mfma_f32_16x16x32_bf16(a1, b, acc[1][s], 0, 0, 0); \
  } }

  floatx4 acc[2][7];
#pragma unroll
  for (int c = 0; c < 2; ++c)
#pragma unroll
    for (int s = 0; s < 7; ++s)
      acc[c][s] = (floatx4){0.f, 0.f, 0.f, 0.f};

  short8 A0, A1, N0, N1;

  // prologue: async-stage ci-block 0 into buffer 0; preload tap0 A-pair.
  STAGE_CB(0, 0);
  LOADA2(A0, A1, 0, 0, quad);
  LOADA2(N0, N1, 0, 1, quad);
  __syncthreads();

#pragma unroll 1
  for (int cb = 0; cb < 4; ++cb) {
    unsigned short* Blds = smem + (cb & 1) * 12288;
    if (cb < 3) { STAGE_CB(cb + 1, (cb + 1) & 1); }   // fire-and-forget
    const int cq8 = cb * 8 + quad;
    int D = 0;
#pragma unroll 1
    for (int t = 0; t < 9; ++t) {
      HALFMMA2(A0, A1, quad, D);                  // uses (t, half0)
      if (t < 8) { LOADA2(A0, A1, t + 1, 0, cq8); }
      HALFMMA2(N0, N1, 4 + quad, D);              // uses (t, half1)
      if (t < 8) { LOADA2(N0, N1, t + 1, 1, cq8); }
      D += (t == 2 || t == 5) ? 28 : 1;
    }
    if (cb < 3) {
      LOADA2(A0, A1, 0, 0, cq8 + 8);              // next cb tap0, pre-barrier
      LOADA2(N0, N1, 0, 1, cq8 + 8);
      __syncthreads();
    }
  }

  // Epilogue. C/D layout: col(sp)=l16, row(co within 16-tile)=quad*4+reg.
  if (STAGE == 1) {
    __syncthreads();   // last cb's Blds reads done before overwrite
#pragma unroll
    for (int c = 0; c < 2; ++c) {
      int co = coW + c * 16 + quad * 4;
      floatx4 As = *(const floatx4*)(bnp + co);
      floatx4 Bs = *(const floatx4*)(bnp + 256 + co);
#pragma unroll
      for (int s = 0; s < 7; ++s) {
        int px = s * 16 + l16;
        ushort4 o;
        o.x = f2bf(fmaxf(acc[c][s][0] * As[0] + Bs[0], 0.f));
        o.y = f2bf(fmaxf(acc[c][s][1] * As[1] + Bs[1], 0.f));
        o.z = f2bf(fmaxf(acc[c][s][2] * As[2] + Bs[2], 0.f));
        o.w = f2bf(fmaxf(acc[c][s][3] * As[3] + Bs[3], 0.f));
        *(ushort4*)&smem[px * 264 + co] = o;
      }
    }
    __syncthreads();
    unsigned short* dst0 = aout + ((size_t)n * 900 + (prow0 + 1) * 30 + 1) * 256;
    for (int u = tid; u < 3584; u += 512) {   // 112 px * 32 groups of 8 co
      int px = u >> 5;
      int c8 = (u & 31) * 8;
      int r  = px / 28;
      int w  = px - r * 28;
      *(short8*)(dst0 + (size_t)(r * 30 + w) * 256 + c8) = *(const short8*)&smem[px * 264 + c8];
    }
  } else {
#pragma unroll
    for (int c = 0; c < 2; ++c) {
      int co = coW + c * 16 + quad * 4;
      floatx4 As = *(const floatx4*)(bnp + 512 + co);
      floatx4 Bs = *(const floatx4*)(bnp + 768 + co);
#pragma unroll
      for (int s = 0; s < 7; ++s) {
        int m = spBlk * 112 + s * 16 + l16;
#pragma unroll
        for (int r = 0; r < 4; ++r) {
          size_t oidx = ((size_t)n * 256 + co + r) * 784 + m;
          float v = acc[c][s][r] * As[r] + Bs[r] + xres[oidx];
          out[oidx] = fmaxf(v, 0.f);
        }
      }
    }
  }
#undef STAGE_CB
#undef LOADA2
#undef HALFMMA2
}

// ---------------- launch ----------------

extern "C" void kernel_launch(void* const* d_in, const int* in_sizes, int n_in,
                              void* d_out, int out_size, void* d_ws, size_t ws_size,
                              hipStream_t stream) {
  const float* x  = (const float*)d_in[0];
  const float* w1 = (const float*)d_in[1];
  const float* g1 = (const float*)d_in[2];
  const float* b1 = (const float*)d_in[3];
  const float* m1 = (const float*)d_in[4];
  const float* v1 = (const float*)d_in[5];
  const float* w2 = (const float*)d_in[6];
  const float* g2 = (const float*)d_in[7];
  const float* b2 = (const float*)d_in[8];
  const float* m2 = (const float*)d_in[9];
  const float* v2 = (const float*)d_in[10];
  float* out = (float*)d_out;

  char* ws = (char*)d_ws;
  const size_t PADBUF = (size_t)64 * 900 * 256 * 2;   // 29,491,200 B
  const size_t WPACK  = 589824ull * 2;                 // 1,179,648 B
  unsigned short* xb   = (unsigned short*)ws;
  unsigned short* abuf = (unsigned short*)(ws + PADBUF);
  unsigned short* ap1  = (unsigned short*)(ws + 2 * PADBUF);
  unsigned short* ap2  = (unsigned short*)(ws + 2 * PADBUF + WPACK);
  float* bnp           = (float*)(ws + 2 * PADBUF + 2 * WPACK);

  prep_all<<<dim3(1920), 256, 0, stream>>>(w1, w2, ap1, ap2,
                                           g1, b1, m1, v1, g2, b2, m2, v2, bnp,
                                           x, xb, abuf);

  dim3 grid(7, 64);   // sp-tile, image
  bconv<1><<<grid, 512, 0, stream>>>(xb,   ap1, bnp, abuf, nullptr, nullptr);
  bconv<2><<<grid, 512, 0, stream>>>(abuf, ap2, bnp, nullptr, x, out);
}